// Round 2
// baseline (498.773 us; speedup 1.0000x reference)
//
#include <hip/hip_runtime.h>
#include <hip/hip_bf16.h>

#define NN 4096     // layer size n
#define RR 4        // displacement rank
#define BB 8192     // batch
#define CHUNK 64            // t-chunk for prefix kernels
#define NCHUNK (NN / CHUNK) // 64

typedef __bf16 bf16x8 __attribute__((ext_vector_type(8)));
typedef float f32x4 __attribute__((ext_vector_type(4)));
typedef unsigned short u16;
typedef unsigned int u32;

#define GLOBAL_AS(p) ((const __attribute__((address_space(1))) u32*)(p))
#define LDS_AS(p) ((__attribute__((address_space(3))) u32*)(p))

__device__ inline u32 pack_bf2(float lo, float hi) {
    __hip_bfloat162 h2 = __float22bfloat162_rn(make_float2(lo, hi));
    return *(u32*)&h2;
}

// ---------------------------------------------------------------------------
// Kernel 0: cast x (f32 row-major) -> bf16 row-major. Pure streaming.
// ---------------------------------------------------------------------------
__global__ __launch_bounds__(256) void cast_x_kernel(const float* __restrict__ x,
                                                     u16* __restrict__ xbf) {
    size_t i = (size_t)blockIdx.x * 256 + threadIdx.x;  // one 8-elem chunk each
    const float4* x4 = (const float4*)x;
    float4 a = x4[i * 2], b = x4[i * 2 + 1];
    uint4 o = make_uint4(pack_bf2(a.x, a.y), pack_bf2(a.z, a.w),
                         pack_bf2(b.x, b.y), pack_bf2(b.z, b.w));
    *(uint4*)(xbf + i * 8) = o;
}

// ---------------------------------------------------------------------------
// Kernel 1: block sums S_T(J,d) = sum_{t in chunk J} q(d,t)   (unchanged)
// ---------------------------------------------------------------------------
__global__ void ksum_kernel(const float* __restrict__ G, const float* __restrict__ H,
                            float* __restrict__ S_T) {
    int dblk = blockIdx.x & 15;
    int J = blockIdx.x >> 4;
    int d = dblk * 256 + threadIdx.x;
    int t0 = J * CHUNK;
    float acc = 0.f;
#pragma unroll 4
    for (int tt = 0; tt < CHUNK; ++tt) {
        int t = t0 + tt;
        float h0 = H[t], h1 = H[NN + t], h2 = H[2 * NN + t], h3 = H[3 * NN + t];
        int idx = (d + t) & (NN - 1);
        acc += G[idx] * h0 + G[NN + idx] * h1 + G[2 * NN + idx] * h2 + G[3 * NN + idx] * h3;
    }
    S_T[J * NN + d] = acc;
}

// ---------------------------------------------------------------------------
// Kernel 2: prefix + W write (bf16 row-major) via LDS tile transpose.
// ---------------------------------------------------------------------------
__global__ __launch_bounds__(128) void kprefix_kernel(const float* __restrict__ G,
                                                      const float* __restrict__ H,
                                                      const float* __restrict__ S_T,
                                                      u16* __restrict__ W) {
    __shared__ u32 tile32[64 * 33];          // row stride 33 u32 = 66 u16
    u16* tile = (u16*)tile32;

    int itile = blockIdx.x >> 6;             // 64 row-tiles
    int J = blockIdx.x & 63;                 // 64 col-chunks
    int i0 = itile * 64, t0 = J * CHUNK;
    int dl = threadIdx.x;                    // 0..127
    int d = (i0 - t0 - 63 + dl) & (NN - 1);

    float pre = 0.f, tot = 0.f;
    for (int Jp = 0; Jp < NCHUNK; ++Jp) {
        float v = S_T[Jp * NN + d];
        if (Jp < J) pre += v;
        tot += v;
    }
    float acc = pre - 0.5f * tot;

#pragma unroll 4
    for (int tt = 0; tt < CHUNK; ++tt) {
        int t = t0 + tt;
        float h0 = H[t], h1 = H[NN + t], h2 = H[2 * NN + t], h3 = H[3 * NN + t];
        int idx = (d + t) & (NN - 1);
        acc += G[idx] * h0 + G[NN + idx] * h1 + G[2 * NN + idx] * h2 + G[3 * NN + idx] * h3;
        int r = dl + tt - 63;                // in-tile row
        if ((unsigned)r < 64u) {
            __hip_bfloat16 w = __float2bfloat16(acc);
            tile[r * 66 + tt] = *(u16*)&w;
        }
    }
    __syncthreads();

    // flush row-major: 16 rows/pass, 8 x 16B per row
    int r = threadIdx.x >> 3;                // 0..15
    int c8 = threadIdx.x & 7;
#pragma unroll
    for (int pass = 0; pass < 4; ++pass) {
        int rr = pass * 16 + r;
        const u32* s = &tile32[rr * 33 + c8 * 4];
        uint4 v = make_uint4(s[0], s[1], s[2], s[3]);
        *(uint4*)(W + (size_t)(i0 + rr) * NN + t0 + c8 * 8) = v;
    }
}

// ---------------------------------------------------------------------------
// Kernel 3: NT GEMM  y[b,i] = sum_j xbf[b,j] * W[i,j]  (f32 out)
// 256x256 tile, BK=64, 8 waves (2M x 4N), 8-phase counted-vmcnt schedule
// + REGISTER-LEVEL fragment double-buffer: ds_reads for phase p+1 are issued
// right after barrier1 of phase p (into the alternate xa/bq bank) and the
// MFMA of phase p waits only lgkmcnt(N_new) -- DS ops retire in order, so
// <= N_new outstanding  ==>  all of phase p's own reads (issued one full
// phase earlier, ~300 cyc ago) are complete. LDS read latency fully hidden.
//
// Hazard ledger (verified):
//  - p3 read-ahead targets cp1 = K-tile 2i+1: published at p3's vmcnt(6)
//    (drain set = ..through A-c1(2i+1)) + barrier1, reads issued AFTER.
//  - p7 read-ahead targets next cp0 = K-tile 2i+2: published at p7's
//    vmcnt(6) (drain set = ..through A-c1(2i+2)) + barrier1.
//  - stage K-tile k events are issued after barrier2 of a phase by which
//    all waves' reads of the overwritten region retired (full barrier gap).
//  - register WAR (read-ahead bank vs current MFMA bank) uses disjoint
//    arrays xa0/xa1, bq0/bq1 with compile-time indices only (rule #20).
// ---------------------------------------------------------------------------

#define ST_A(kt, c) do { \
    const u16* s_ = srcA + (size_t)(c) * (64 * NN) + (size_t)(kt) * 64; \
    char* d_ = (char*)As + (((kt) & 1) * 32768) + ((c) * 8192) + t16; \
    __builtin_amdgcn_global_load_lds(GLOBAL_AS(s_), LDS_AS(d_), 16, 0, 0); \
    __builtin_amdgcn_global_load_lds(GLOBAL_AS(s_ + (size_t)128 * NN), LDS_AS(d_ + 16384), 16, 0, 0); \
} while (0)

#define ST_B(kt, hb) do { \
    const u16* s_ = srcB + (size_t)(hb) * (128 * NN) + (size_t)(kt) * 64; \
    char* d_ = (char*)Bs + (((kt) & 1) * 32768) + ((hb) * 16384) + t16; \
    __builtin_amdgcn_global_load_lds(GLOBAL_AS(s_), LDS_AS(d_), 16, 0, 0); \
    __builtin_amdgcn_global_load_lds(GLOBAL_AS(s_ + (size_t)64 * NN), LDS_AS(d_ + 8192), 16, 0, 0); \
} while (0)

#define AFR(cp, mi, ks) (*(const bf16x8*)(Abase + (cp) * 32768 + (mi) * 2048 + (sx ^ ((ks) << 6))))
#define BFR(cp, ni, ks) (*(const bf16x8*)(Bbase + (cp) * 32768 + (ni) * 2048 + (sx ^ ((ks) << 6))))

#define LDXA(XA, cp, mp) do { \
    XA[0] = AFR(cp, mp, 0); XA[1] = AFR(cp, mp, 1); \
    XA[2] = AFR(cp, (mp) + 1, 0); XA[3] = AFR(cp, (mp) + 1, 1); \
} while (0)

#define LDBQ(BQ, cp) do { \
    BQ[0] = BFR(cp, 0, 0); BQ[1] = BFR(cp, 0, 1); \
    BQ[2] = BFR(cp, 1, 0); BQ[3] = BFR(cp, 1, 1); \
    BQ[4] = BFR(cp, 2, 0); BQ[5] = BFR(cp, 2, 1); \
    BQ[6] = BFR(cp, 3, 0); BQ[7] = BFR(cp, 3, 1); \
} while (0)

#define MFMA_(a, b, c) __builtin_amdgcn_mfma_f32_16x16x32_bf16(a, b, c, 0, 0, 0)

#define MM1(mi, ni, A0, A1, BQ) do { \
    acc[mi][ni] = MFMA_(A0, BQ[2 * (ni)], acc[mi][ni]); \
    acc[mi][ni] = MFMA_(A1, BQ[2 * (ni) + 1], acc[mi][ni]); \
} while (0)

#define MMQ(mp, XA, BQ) do { \
    MM1(mp, 0, XA[0], XA[1], BQ); MM1(mp, 1, XA[0], XA[1], BQ); \
    MM1(mp, 2, XA[0], XA[1], BQ); MM1(mp, 3, XA[0], XA[1], BQ); \
    MM1((mp) + 1, 0, XA[2], XA[3], BQ); MM1((mp) + 1, 1, XA[2], XA[3], BQ); \
    MM1((mp) + 1, 2, XA[2], XA[3], BQ); MM1((mp) + 1, 3, XA[2], XA[3], BQ); \
} while (0)

#define VMC(n) asm volatile("s_waitcnt vmcnt(" #n ")" ::: "memory")

// phase: STAGES; [vmcnt]; barrier1; read-ahead (next bank); lgkmcnt(Nnew);
//        setprio(1); 16 MFMA (current bank); setprio(0); barrier2.
#define PH_BODY(mp, XAc, BQc, RA, NLG, STAGES, WAITC) do { \
    STAGES; \
    WAITC; \
    __builtin_amdgcn_s_barrier(); \
    __builtin_amdgcn_sched_barrier(0); \
    RA; \
    asm volatile("s_waitcnt lgkmcnt(" NLG ")" ::: "memory"); \
    __builtin_amdgcn_sched_barrier(0); \
    __builtin_amdgcn_s_setprio(1); \
    MMQ(mp, XAc, BQc); \
    __builtin_amdgcn_s_setprio(0); \
    __builtin_amdgcn_s_barrier(); \
    __builtin_amdgcn_sched_barrier(0); \
} while (0)

__global__ __launch_bounds__(512, 2) void gemm256_kernel(const u16* __restrict__ At,
                                                         const u16* __restrict__ Bt,
                                                         float* __restrict__ C) {
    __shared__ __align__(16) u16 As[2][2][2][64][64];  // 64 KiB
    __shared__ __align__(16) u16 Bs[2][2][2][64][64];  // 64 KiB

    // T1: XCD-aware swizzle; nwg = 512, 512 % 8 == 0 -> simple bijection
    int bid = blockIdx.x;
    int swz = (bid & 7) * 64 + (bid >> 3);
    int bx = swz & 15, by = swz >> 4;       // each XCD: 4 M-panels x all 16 N
    int m0 = by * 256, n0 = bx * 256;

    int t = threadIdx.x;
    int lane = t & 63, wave = t >> 6;
    int wm = wave >> 2, wn = wave & 3;      // 2M x 4N waves; per-wave C: 128x64
    int lrow = lane & 15, lq = lane >> 4;

    // staging: thread t covers linear LDS bytes [t*16); source col pre-swizzled
    int rowt = t >> 3;                                  // 0..63
    int colel = ((t & 7) ^ (rowt & 7)) << 3;            // element offset
    const u16* srcA = At + (size_t)(m0 + rowt) * NN + colel;
    const u16* srcB = Bt + (size_t)(n0 + rowt) * NN + colel;
    int t16 = t * 16;

    // ds_read bases (swizzled): frag byte = row*128 + ((lq<<4 | ks<<6) ^ ((row&7)<<4))
    const char* Abase = (const char*)As + wm * 16384 + lrow * 128;
    const char* Bbase = (const char*)Bs + (wn >> 1) * 16384 + (wn & 1) * 8192 + lrow * 128;
    int sx = (lq << 4) ^ ((lrow & 7) << 4);

    f32x4 acc[8][4] = {};
    bf16x8 xa0[4], xa1[4], bq0[8], bq1[8];

    // prologue: K-tile 0 fully, K-tile 1 all but A-chunk1; 3 events in flight
    ST_B(0, 0); ST_B(0, 1); ST_A(0, 0); ST_A(0, 1);
    ST_B(1, 0); ST_B(1, 1); ST_A(1, 0);
    VMC(6);                                  // drains all of K-tile 0
    __builtin_amdgcn_s_barrier();
    __builtin_amdgcn_sched_barrier(0);
    LDBQ(bq0, 0);                            // reads for phase 0 (12 total)
    LDXA(xa0, 0, 0);

#pragma unroll 1
    for (int i = 0; i < 31; ++i) {
        int k0 = 2 * i;
        PH_BODY(0, xa0, bq0, LDXA(xa1, 0, 2), "4", ST_A(k0 + 1, 1), );
        PH_BODY(2, xa1, bq0, LDXA(xa0, 0, 4), "4", ST_B(k0 + 2, 0), );
        PH_BODY(4, xa0, bq0, LDXA(xa1, 0, 6), "4", ST_B(k0 + 2, 1), );
        PH_BODY(6, xa1, bq0, { LDBQ(bq1, 1); LDXA(xa0, 1, 0); }, "12",
                ST_A(k0 + 2, 0), VMC(6));
        PH_BODY(0, xa0, bq1, LDXA(xa1, 1, 2), "4", ST_A(k0 + 2, 1), );
        PH_BODY(2, xa1, bq1, LDXA(xa0, 1, 4), "4", ST_B(k0 + 3, 0), );
        PH_BODY(4, xa0, bq1, LDXA(xa1, 1, 6), "4", ST_B(k0 + 3, 1), );
        PH_BODY(6, xa1, bq1, { LDBQ(bq0, 0); LDXA(xa0, 0, 0); }, "12",
                ST_A(k0 + 3, 0), VMC(6));
    }
    // peeled final iteration: K-tiles 62 (cp0), 63 (cp1); drain vmcnt to 0
    PH_BODY(0, xa0, bq0, LDXA(xa1, 0, 2), "4", ST_A(63, 1), );
    PH_BODY(2, xa1, bq0, LDXA(xa0, 0, 4), "4", , );
    PH_BODY(4, xa0, bq0, LDXA(xa1, 0, 6), "4", , );
    PH_BODY(6, xa1, bq0, { LDBQ(bq1, 1); LDXA(xa0, 1, 0); }, "12", , VMC(0));
    PH_BODY(0, xa0, bq1, LDXA(xa1, 1, 2), "4", , );
    PH_BODY(2, xa1, bq1, LDXA(xa0, 1, 4), "4", , );
    PH_BODY(4, xa0, bq1, LDXA(xa1, 1, 6), "4", , );
    PH_BODY(6, xa1, bq1, , "0", , );

    // epilogue: D layout col=lane&15, row=(lane>>4)*4+e
#pragma unroll
    for (int mi = 0; mi < 8; ++mi)
#pragma unroll
        for (int ni = 0; ni < 4; ++ni)
#pragma unroll
            for (int e = 0; e < 4; ++e) {
                int row = m0 + wm * 128 + mi * 16 + lq * 4 + e;
                int col = n0 + wn * 64 + ni * 16 + lrow;
                C[(size_t)row * NN + col] = acc[mi][ni][e];
            }
}

// ---------------------------------------------------------------------------
extern "C" void kernel_launch(void* const* d_in, const int* in_sizes, int n_in,
                              void* d_out, int out_size, void* d_ws, size_t ws_size,
                              hipStream_t stream) {
    const float* x = (const float*)d_in[0];
    const float* G = (const float*)d_in[1];
    const float* H = (const float*)d_in[2];
    float* y = (float*)d_out;

    char* ws = (char*)d_ws;
    u16* xbf = (u16*)ws;                                   // 64 MB, row-major
    u16* Wbf = (u16*)(ws + (size_t)BB * NN * 2);           // 32 MB, row-major
    float* S_T = (float*)(ws + (size_t)BB * NN * 2 + (size_t)NN * NN * 2);  // 1 MB

    hipLaunchKernelGGL(cast_x_kernel, dim3((size_t)BB * NN / 8 / 256), dim3(256), 0, stream,
                       x, xbf);
    hipLaunchKernelGGL(ksum_kernel, dim3((NN / 256) * NCHUNK), dim3(256), 0, stream, G, H, S_T);
    hipLaunchKernelGGL(kprefix_kernel, dim3(64 * 64), dim3(128), 0, stream, G, H, S_T, Wbf);
    hipLaunchKernelGGL(gemm256_kernel, dim3((BB / 256) * (NN / 256)), dim3(512), 0, stream,
                       xbf, Wbf, y);
}

// Round 3
// 489.177 us; speedup vs baseline: 1.0196x; 1.0196x over previous
//
#include <hip/hip_runtime.h>
#include <hip/hip_bf16.h>

#define NN 4096     // layer size n
#define RR 4        // displacement rank
#define BB 8192     // batch
#define CHUNK 64            // t-chunk for prefix kernels
#define NCHUNK (NN / CHUNK) // 64

typedef __bf16 bf16x8 __attribute__((ext_vector_type(8)));
typedef float f32x4 __attribute__((ext_vector_type(4)));
typedef unsigned short u16;
typedef unsigned int u32;

#define GLOBAL_AS(p) ((const __attribute__((address_space(1))) u32*)(p))
#define LDS_AS(p) ((__attribute__((address_space(3))) u32*)(p))

__device__ inline u32 pack_bf2(float lo, float hi) {
    __hip_bfloat162 h2 = __float22bfloat162_rn(make_float2(lo, hi));
    return *(u32*)&h2;
}

// ---------------------------------------------------------------------------
// Kernel 0: cast x (f32 row-major) -> bf16 row-major. Pure streaming.
// ---------------------------------------------------------------------------
__global__ __launch_bounds__(256) void cast_x_kernel(const float* __restrict__ x,
                                                     u16* __restrict__ xbf) {
    size_t i = (size_t)blockIdx.x * 256 + threadIdx.x;  // one 8-elem chunk each
    const float4* x4 = (const float4*)x;
    float4 a = x4[i * 2], b = x4[i * 2 + 1];
    uint4 o = make_uint4(pack_bf2(a.x, a.y), pack_bf2(a.z, a.w),
                         pack_bf2(b.x, b.y), pack_bf2(b.z, b.w));
    *(uint4*)(xbf + i * 8) = o;
}

// ---------------------------------------------------------------------------
// Kernel 1: block sums S_T(J,d) = sum_{t in chunk J} q(d,t)
// ---------------------------------------------------------------------------
__global__ void ksum_kernel(const float* __restrict__ G, const float* __restrict__ H,
                            float* __restrict__ S_T) {
    int dblk = blockIdx.x & 15;
    int J = blockIdx.x >> 4;
    int d = dblk * 256 + threadIdx.x;
    int t0 = J * CHUNK;
    float acc = 0.f;
#pragma unroll 4
    for (int tt = 0; tt < CHUNK; ++tt) {
        int t = t0 + tt;
        float h0 = H[t], h1 = H[NN + t], h2 = H[2 * NN + t], h3 = H[3 * NN + t];
        int idx = (d + t) & (NN - 1);
        acc += G[idx] * h0 + G[NN + idx] * h1 + G[2 * NN + idx] * h2 + G[3 * NN + idx] * h3;
    }
    S_T[J * NN + d] = acc;
}

// ---------------------------------------------------------------------------
// Kernel 2: prefix + W write (bf16 row-major) via LDS tile transpose.
// ---------------------------------------------------------------------------
__global__ __launch_bounds__(128) void kprefix_kernel(const float* __restrict__ G,
                                                      const float* __restrict__ H,
                                                      const float* __restrict__ S_T,
                                                      u16* __restrict__ W) {
    __shared__ u32 tile32[64 * 33];          // row stride 33 u32 = 66 u16
    u16* tile = (u16*)tile32;

    int itile = blockIdx.x >> 6;             // 64 row-tiles
    int J = blockIdx.x & 63;                 // 64 col-chunks
    int i0 = itile * 64, t0 = J * CHUNK;
    int dl = threadIdx.x;                    // 0..127
    int d = (i0 - t0 - 63 + dl) & (NN - 1);

    float pre = 0.f, tot = 0.f;
    for (int Jp = 0; Jp < NCHUNK; ++Jp) {
        float v = S_T[Jp * NN + d];
        if (Jp < J) pre += v;
        tot += v;
    }
    float acc = pre - 0.5f * tot;

#pragma unroll 4
    for (int tt = 0; tt < CHUNK; ++tt) {
        int t = t0 + tt;
        float h0 = H[t], h1 = H[NN + t], h2 = H[2 * NN + t], h3 = H[3 * NN + t];
        int idx = (d + t) & (NN - 1);
        acc += G[idx] * h0 + G[NN + idx] * h1 + G[2 * NN + idx] * h2 + G[3 * NN + idx] * h3;
        int r = dl + tt - 63;                // in-tile row
        if ((unsigned)r < 64u) {
            __hip_bfloat16 w = __float2bfloat16(acc);
            tile[r * 66 + tt] = *(u16*)&w;
        }
    }
    __syncthreads();

    // flush row-major: 16 rows/pass, 8 x 16B per row
    int r = threadIdx.x >> 3;                // 0..15
    int c8 = threadIdx.x & 7;
#pragma unroll
    for (int pass = 0; pass < 4; ++pass) {
        int rr = pass * 16 + r;
        const u32* s = &tile32[rr * 33 + c8 * 4];
        uint4 v = make_uint4(s[0], s[1], s[2], s[3]);
        *(uint4*)(W + (size_t)(i0 + rr) * NN + t0 + c8 * 8) = v;
    }
}

// ---------------------------------------------------------------------------
// Kernel 3: NT GEMM  y[b,i] = sum_j xbf[b,j] * W[i,j]  (f32 out)
// 256x256 tile, BK=64, 8 waves (2M x 4N), 4-PHASE counted-vmcnt schedule.
// R1 skeleton (reads pre-barrier, lgkmcnt(0) post-barrier) with phases
// merged 8->4: 32 MFMA per phase amortizes the ~170-cyc fixed per-phase
// overhead (read-issue + barrier + drain) over 2x the matrix work.
//
// Per iteration i (K-tiles 2i par0, 2i+1 par1):
//  P0: reads bq(par0)+xa(mi0-3,par0) [16]; stage A1(2i+1);            MFMA mi0-3
//  P1: reads xa(mi4-7,par0) [8]; stage B0,B1,A0(2i+2); vmcnt(6);      MFMA mi4-7
//  P2: reads bq(par1)+xa(mi0-3,par1) [16]; stage A1(2i+2);            MFMA mi0-3
//  P3: reads xa(mi4-7,par1) [8]; stage B0,B1,A0(2i+3); vmcnt(6);      MFMA mi4-7
// vmcnt(6)@P1 leaves P1's own 3 events -> tile 2i+1 drained before P2/P3
// read it; vmcnt(6)@P3 drains tile 2i+2 before next P0/P1. Every stage
// overwrites a region whose last ds_read was >=1 full barrier earlier.
// bq is loaded once per K-tile (P0/P2) and reused by the odd phase.
// ---------------------------------------------------------------------------

#define ST_A(kt, c) do { \
    const u16* s_ = srcA + (size_t)(c) * (64 * NN) + (size_t)(kt) * 64; \
    char* d_ = (char*)As + (((kt) & 1) * 32768) + ((c) * 8192) + t16; \
    __builtin_amdgcn_global_load_lds(GLOBAL_AS(s_), LDS_AS(d_), 16, 0, 0); \
    __builtin_amdgcn_global_load_lds(GLOBAL_AS(s_ + (size_t)128 * NN), LDS_AS(d_ + 16384), 16, 0, 0); \
} while (0)

#define ST_B(kt, hb) do { \
    const u16* s_ = srcB + (size_t)(hb) * (128 * NN) + (size_t)(kt) * 64; \
    char* d_ = (char*)Bs + (((kt) & 1) * 32768) + ((hb) * 16384) + t16; \
    __builtin_amdgcn_global_load_lds(GLOBAL_AS(s_), LDS_AS(d_), 16, 0, 0); \
    __builtin_amdgcn_global_load_lds(GLOBAL_AS(s_ + (size_t)64 * NN), LDS_AS(d_ + 8192), 16, 0, 0); \
} while (0)

#define AFR(cp, mi, ks) (*(const bf16x8*)(Abase + (cp) * 32768 + (mi) * 2048 + (sx ^ ((ks) << 6))))
#define BFR(cp, ni, ks) (*(const bf16x8*)(Bbase + (cp) * 32768 + (ni) * 2048 + (sx ^ ((ks) << 6))))

#define LDXA4(cp, mb) do { \
    xa[0] = AFR(cp, (mb) + 0, 0); xa[1] = AFR(cp, (mb) + 0, 1); \
    xa[2] = AFR(cp, (mb) + 1, 0); xa[3] = AFR(cp, (mb) + 1, 1); \
    xa[4] = AFR(cp, (mb) + 2, 0); xa[5] = AFR(cp, (mb) + 2, 1); \
    xa[6] = AFR(cp, (mb) + 3, 0); xa[7] = AFR(cp, (mb) + 3, 1); \
} while (0)

#define LDBQ(cp) do { \
    bq[0] = BFR(cp, 0, 0); bq[1] = BFR(cp, 0, 1); \
    bq[2] = BFR(cp, 1, 0); bq[3] = BFR(cp, 1, 1); \
    bq[4] = BFR(cp, 2, 0); bq[5] = BFR(cp, 2, 1); \
    bq[6] = BFR(cp, 3, 0); bq[7] = BFR(cp, 3, 1); \
} while (0)

#define MFMA_(a, b, c) __builtin_amdgcn_mfma_f32_16x16x32_bf16(a, b, c, 0, 0, 0)

#define MM1(mi, ni, A0, A1) do { \
    acc[mi][ni] = MFMA_(A0, bq[2 * (ni)], acc[mi][ni]); \
    acc[mi][ni] = MFMA_(A1, bq[2 * (ni) + 1], acc[mi][ni]); \
} while (0)

// 32 MFMA: mi = mb..mb+3, ni = 0..3, ks folded into MM1
#define MMH(mb) do { \
    MM1((mb) + 0, 0, xa[0], xa[1]); MM1((mb) + 0, 1, xa[0], xa[1]); \
    MM1((mb) + 0, 2, xa[0], xa[1]); MM1((mb) + 0, 3, xa[0], xa[1]); \
    MM1((mb) + 1, 0, xa[2], xa[3]); MM1((mb) + 1, 1, xa[2], xa[3]); \
    MM1((mb) + 1, 2, xa[2], xa[3]); MM1((mb) + 1, 3, xa[2], xa[3]); \
    MM1((mb) + 2, 0, xa[4], xa[5]); MM1((mb) + 2, 1, xa[4], xa[5]); \
    MM1((mb) + 2, 2, xa[4], xa[5]); MM1((mb) + 2, 3, xa[4], xa[5]); \
    MM1((mb) + 3, 0, xa[6], xa[7]); MM1((mb) + 3, 1, xa[6], xa[7]); \
    MM1((mb) + 3, 2, xa[6], xa[7]); MM1((mb) + 3, 3, xa[6], xa[7]); \
} while (0)

#define VMC(n) asm volatile("s_waitcnt vmcnt(" #n ")" ::: "memory")
#define LGK(n) asm volatile("s_waitcnt lgkmcnt(" #n ")" ::: "memory")

// phase: READS (pre-barrier); STAGES; [lgkm-hint]; [vmcnt]; barrier1;
//        lgkmcnt(0); setprio(1); 32 MFMA; setprio(0); barrier2.
#define PH4(mb, READS, STAGES, HINT, WAITC) do { \
    READS; \
    STAGES; \
    HINT; \
    WAITC; \
    __builtin_amdgcn_s_barrier(); \
    LGK(0); \
    __builtin_amdgcn_sched_barrier(0); \
    __builtin_amdgcn_s_setprio(1); \
    MMH(mb); \
    __builtin_amdgcn_s_setprio(0); \
    __builtin_amdgcn_s_barrier(); \
    __builtin_amdgcn_sched_barrier(0); \
} while (0)

__global__ __launch_bounds__(512, 2) void gemm256_kernel(const u16* __restrict__ At,
                                                         const u16* __restrict__ Bt,
                                                         float* __restrict__ C) {
    __shared__ __align__(16) u16 As[2][2][2][64][64];  // 64 KiB
    __shared__ __align__(16) u16 Bs[2][2][2][64][64];  // 64 KiB

    // T1: XCD-aware swizzle; nwg = 512, 512 % 8 == 0 -> simple bijection
    int bid = blockIdx.x;
    int swz = (bid & 7) * 64 + (bid >> 3);
    int bx = swz & 15, by = swz >> 4;       // each XCD: 4 M-panels x all 16 N
    int m0 = by * 256, n0 = bx * 256;

    int t = threadIdx.x;
    int lane = t & 63, wave = t >> 6;
    int wm = wave >> 2, wn = wave & 3;      // 2M x 4N waves; per-wave C: 128x64
    int lrow = lane & 15, lq = lane >> 4;

    // staging: thread t covers linear LDS bytes [t*16); source col pre-swizzled
    int rowt = t >> 3;                                  // 0..63
    int colel = ((t & 7) ^ (rowt & 7)) << 3;            // element offset
    const u16* srcA = At + (size_t)(m0 + rowt) * NN + colel;
    const u16* srcB = Bt + (size_t)(n0 + rowt) * NN + colel;
    int t16 = t * 16;

    // ds_read bases (swizzled): frag byte = row*128 + ((lq<<4 | ks<<6) ^ ((row&7)<<4))
    const char* Abase = (const char*)As + wm * 16384 + lrow * 128;
    const char* Bbase = (const char*)Bs + (wn >> 1) * 16384 + (wn & 1) * 8192 + lrow * 128;
    int sx = (lq << 4) ^ ((lrow & 7) << 4);

    f32x4 acc[8][4] = {};
    bf16x8 xa[8], bq[8];

    // prologue: tile 0 fully, tile 1 all but A-chunk1; 3 events (6 loads) in flight
    ST_B(0, 0); ST_B(0, 1); ST_A(0, 0); ST_A(0, 1);
    ST_B(1, 0); ST_B(1, 1); ST_A(1, 0);
    VMC(6);                                  // drains all of K-tile 0
    __builtin_amdgcn_s_barrier();
    __builtin_amdgcn_sched_barrier(0);

#pragma unroll 1
    for (int i = 0; i < 31; ++i) {
        int k0 = 2 * i;
        PH4(0, { LDBQ(0); LDXA4(0, 0); }, ST_A(k0 + 1, 1), LGK(8), );
        PH4(4, LDXA4(0, 4),
             { ST_B(k0 + 2, 0); ST_B(k0 + 2, 1); ST_A(k0 + 2, 0); }, , VMC(6));
        PH4(0, { LDBQ(1); LDXA4(1, 0); }, ST_A(k0 + 2, 1), LGK(8), );
        PH4(4, LDXA4(1, 4),
             { ST_B(k0 + 3, 0); ST_B(k0 + 3, 1); ST_A(k0 + 3, 0); }, , VMC(6));
    }
    // peeled final iteration: K-tiles 62 (par0), 63 (par1)
    PH4(0, { LDBQ(0); LDXA4(0, 0); }, ST_A(63, 1), LGK(8), );
    PH4(4, LDXA4(0, 4), , , VMC(0));
    PH4(0, { LDBQ(1); LDXA4(1, 0); }, , LGK(8), );
    PH4(4, LDXA4(1, 4), , , );

    // epilogue: D layout col=lane&15, row=(lane>>4)*4+e
#pragma unroll
    for (int mi = 0; mi < 8; ++mi)
#pragma unroll
        for (int ni = 0; ni < 4; ++ni)
#pragma unroll
            for (int e = 0; e < 4; ++e) {
                int row = m0 + wm * 128 + mi * 16 + lq * 4 + e;
                int col = n0 + wn * 64 + ni * 16 + lrow;
                C[(size_t)row * NN + col] = acc[mi][ni][e];
            }
}

// ---------------------------------------------------------------------------
extern "C" void kernel_launch(void* const* d_in, const int* in_sizes, int n_in,
                              void* d_out, int out_size, void* d_ws, size_t ws_size,
                              hipStream_t stream) {
    const float* x = (const float*)d_in[0];
    const float* G = (const float*)d_in[1];
    const float* H = (const float*)d_in[2];
    float* y = (float*)d_out;

    char* ws = (char*)d_ws;
    u16* xbf = (u16*)ws;                                   // 64 MB, row-major
    u16* Wbf = (u16*)(ws + (size_t)BB * NN * 2);           // 32 MB, row-major
    float* S_T = (float*)(ws + (size_t)BB * NN * 2 + (size_t)NN * NN * 2);  // 1 MB

    hipLaunchKernelGGL(cast_x_kernel, dim3((size_t)BB * NN / 8 / 256), dim3(256), 0, stream,
                       x, xbf);
    hipLaunchKernelGGL(ksum_kernel, dim3((NN / 256) * NCHUNK), dim3(256), 0, stream, G, H, S_T);
    hipLaunchKernelGGL(kprefix_kernel, dim3(64 * 64), dim3(128), 0, stream, G, H, S_T, Wbf);
    hipLaunchKernelGGL(gemm256_kernel, dim3((BB / 256) * (NN / 256)), dim3(512), 0, stream,
                       xbf, Wbf, y);
}